// Round 12
// baseline (207.696 us; speedup 1.0000x reference)
//
#include <hip/hip_runtime.h>
#include <hip/hip_bf16.h>
#include <stdint.h>
#include <stddef.h>

typedef __bf16 bf16_t;
typedef __bf16 bf16x8 __attribute__((ext_vector_type(8)));
typedef __bf16 bf16x4 __attribute__((ext_vector_type(4)));
typedef float  f32x4  __attribute__((ext_vector_type(4)));

static __device__ __forceinline__ f32x4 mfma16x16x32(bf16x8 a, bf16x8 b, f32x4 c) {
  return __builtin_amdgcn_mfma_f32_16x16x32_bf16(a, b, c, 0, 0, 0);
}

static __device__ __forceinline__ void gld_lds16(const void* g, void* l) {
  __builtin_amdgcn_global_load_lds(
      (const __attribute__((address_space(1))) unsigned int*)g,
      (__attribute__((address_space(3))) unsigned int*)l, 16, 0, 0);
}

#define BARW()   __builtin_amdgcn_s_barrier()
#define SCHED0() __builtin_amdgcn_sched_barrier(0)
#define LGKM0()  asm volatile("s_waitcnt lgkmcnt(0)" ::: "memory")
#define LGKMN(n) asm volatile("s_waitcnt lgkmcnt(" #n ")" ::: "memory")
#define VMCNT(n) asm volatile("s_waitcnt vmcnt(" #n ")" ::: "memory")
#define PRIO(p)  __builtin_amdgcn_s_setprio(p)

// ---------------------------------------------------------------- merged prep:
// [0,2048): fuse_w (16 combos x 16 kt x 8 fq) ; [2048,2304): cvt w_out ;
// [2304,2560): cvt Wv ; [2560,3584): cvt x
__global__ __launch_bounds__(256) void prep(const float* __restrict__ wqkv,
                                            const float* __restrict__ proj,
                                            const float* __restrict__ wout,
                                            const float* __restrict__ x,
                                            bf16_t* __restrict__ B1t2,
                                            bf16_t* __restrict__ Wv,
                                            bf16_t* __restrict__ W3t,
                                            bf16_t* __restrict__ xbf) {
  const int b = blockIdx.x;
  const int tid = threadIdx.x;
  if (b >= 2560) {
    for (int i = (b - 2560) * 256 + tid; i < 4194304; i += 262144) {
      float4 v = *(const float4*)(x + (size_t)i * 4);
      bf16x4 o;
      o[0] = (bf16_t)v.x; o[1] = (bf16_t)v.y; o[2] = (bf16_t)v.z; o[3] = (bf16_t)v.w;
      *(bf16x4*)(xbf + (size_t)i * 4) = o;
    }
    return;
  }
  if (b >= 2048) {
    const float* src = (b < 2304) ? wout : (wqkv + (size_t)2048 * 1024);
    bf16_t* dst = (b < 2304) ? W3t : Wv;
    size_t off = ((size_t)((b - 2048) & 255) * 4096) + tid * 16;
#pragma unroll
    for (int it = 0; it < 4; ++it) {
      float4 v = *(const float4*)(src + off + it * 4);
      bf16x4 o;
      o[0] = (bf16_t)v.x; o[1] = (bf16_t)v.y; o[2] = (bf16_t)v.z; o[3] = (bf16_t)v.w;
      *(bf16x4*)(dst + off + it * 4) = o;
    }
    return;
  }
  // fuse_w: B1t2[h*256 + qk*128 + f][k] = sum_c wqkv[(qk*1024+h*128+c)][k] * proj[h][c][f]
  const int combo = b >> 7;            // 0..15
  const int kt    = (b >> 3) & 15;
  const int fq    = b & 7;
  const int qk    = combo >> 3;
  const int h     = combo & 7;
  const int klocal = tid & 63;
  const int fg     = tid >> 6;         // 0..3
  const int k      = kt * 64 + klocal;
  const int f0     = fq * 16 + fg * 4;

  const float* wbase = wqkv + ((size_t)(qk * 1024 + h * 128)) * 1024 + k;
  const float* pbase = proj + (size_t)h * 16384 + f0;

  float acc[4] = {0.f, 0.f, 0.f, 0.f};

  for (int c = 0; c < 128; ++c) {
    float a = wbase[(size_t)c * 1024];
    float4 p0 = *(const float4*)(pbase + (size_t)c * 128);
    acc[0] += a * p0.x; acc[1] += a * p0.y; acc[2] += a * p0.z; acc[3] += a * p0.w;
  }
  bf16_t* obase = B1t2 + ((size_t)(h * 256 + qk * 128 + f0)) * 1024 + k;
#pragma unroll
  for (int i = 0; i < 4; ++i) obase[(size_t)i * 1024] = (bf16_t)acc[i];
}

// ================================================================ shared main-loop macros
#define GEMM_MAINLOOP_DECLS()                                                  \
  const int tid  = threadIdx.x;                                                \
  const int lane = tid & 63;                                                   \
  const int wid  = tid >> 6;                                                   \
  const int wm   = wid >> 2;                                                   \
  const int wn   = wid & 3;                                                    \
  const int lr   = lane & 15;                                                  \
  const int g0   = lane >> 4;                                                  \
  int srow[2], sgl[2];                                                         \
  _Pragma("unroll")                                                            \
  for (int l = 0; l < 2; ++l) {                                                \
    int idx = l * 512 + tid;                                                   \
    srow[l] = idx >> 3;                                                        \
    sgl[l]  = (idx & 7) ^ (srow[l] & 7);                                       \
  }

// arr must be a 2D slice: sA[buf] / sB[buf]
#define STAGE_T(arr, base, half, kt, K_)                                       \
  {                                                                            \
    const bf16_t* s_ = (base) + (size_t)((half) * 128) * (K_) + (kt) * 64;     \
    bf16_t* d_ = &(arr)[half][0];                                              \
    _Pragma("unroll")                                                          \
    for (int l_ = 0; l_ < 2; ++l_)                                             \
      gld_lds16(s_ + (size_t)srow[l_] * (K_) + sgl[l_] * 8,                    \
                d_ + (l_ * 512 + tid) * 8);                                    \
  }

#define RD_A(buf, qm)                                                          \
  _Pragma("unroll")                                                            \
  for (int t_ = 0; t_ < 4; ++t_) {                                             \
    int r_ = (qm) * 64 + t_ * 16 + lr;                                         \
    _Pragma("unroll")                                                          \
    for (int kh_ = 0; kh_ < 2; ++kh_) {                                        \
      int gl_ = (g0 + kh_ * 4) ^ (r_ & 7);                                     \
      a[t_][kh_] = *(const bf16x8*)(&sA[buf][wm][r_ * 64 + gl_ * 8]);          \
    }                                                                          \
  }
#define RD_B(buf, qn, breg)                                                    \
  _Pragma("unroll")                                                            \
  for (int u_ = 0; u_ < 2; ++u_) {                                             \
    int r_ = (wn & 1) * 64 + (qn) * 32 + u_ * 16 + lr;                         \
    _Pragma("unroll")                                                          \
    for (int kh_ = 0; kh_ < 2; ++kh_) {                                        \
      int gl_ = (g0 + kh_ * 4) ^ (r_ & 7);                                     \
      breg[u_][kh_] = *(const bf16x8*)(&sB[buf][wn >> 1][r_ * 64 + gl_ * 8]);  \
    }                                                                          \
  }
#define MMA(qm, qn, breg)                                                      \
  _Pragma("unroll")                                                            \
  for (int mi_ = 0; mi_ < 4; ++mi_)                                            \
    _Pragma("unroll")                                                          \
    for (int nj_ = 0; nj_ < 2; ++nj_)                                          \
      _Pragma("unroll")                                                        \
      for (int kh_ = 0; kh_ < 2; ++kh_)                                        \
        acc[(qm) * 4 + mi_][(qn) * 2 + nj_] =                                  \
            mfma16x16x32(a[mi_][kh_], breg[nj_][kh_],                          \
                         acc[(qm) * 4 + mi_][(qn) * 2 + nj_]);

// R5 4-phase schedule, SCHED0-diet (matches m201 template: bare barriers + asm
// waits + setprio only; no sched_barrier in the hot loop)
#define GEMM_MAINLOOP_BODY(Abase, Bbase, K_, NT_)                              \
  f32x4 acc[8][4] = {};                                                        \
  bf16x8 a[4][2], b0[2][2], b1[2][2];                                          \
  STAGE_T(sA[0], Abase, 0, 0, K_); STAGE_T(sA[0], Abase, 1, 0, K_);            \
  STAGE_T(sB[0], Bbase, 0, 0, K_); STAGE_T(sB[0], Bbase, 1, 0, K_);            \
  STAGE_T(sA[1], Abase, 0, 1, K_); STAGE_T(sA[1], Abase, 1, 1, K_);            \
  STAGE_T(sB[1], Bbase, 0, 1, K_); STAGE_T(sB[1], Bbase, 1, 1, K_);            \
  VMCNT(8);                                                                    \
  BARW();                                                                      \
  _Pragma("unroll 2")                                                          \
  for (int j = 0; j < (NT_); ++j) {                                            \
    const int cur = j & 1;                                                     \
    const bool pf = (j + 2) < (NT_);                                           \
    RD_A(cur, 0);                                                              \
    RD_B(cur, 0, b0);                                                          \
    LGKMN(8); BARW(); LGKM0();                                                 \
    PRIO(1); MMA(0, 0, b0); PRIO(0);                                           \
    BARW();                                                                    \
    RD_B(cur, 1, b1);                                                          \
    BARW(); LGKM0();                                                           \
    PRIO(1); MMA(0, 1, b1); PRIO(0);                                           \
    BARW();                                                                    \
    RD_A(cur, 1);                                                              \
    if (pf) { STAGE_T(sB[cur], Bbase, 0, j + 2, K_); STAGE_T(sB[cur], Bbase, 1, j + 2, K_); } \
    LGKMN(4); BARW(); LGKM0();                                                 \
    PRIO(1); MMA(1, 1, b1); PRIO(0);                                           \
    BARW();                                                                    \
    if (pf) { STAGE_T(sA[cur], Abase, 0, j + 2, K_); STAGE_T(sA[cur], Abase, 1, j + 2, K_); } \
    BARW();                                                                    \
    PRIO(1); MMA(1, 0, b0); PRIO(0);                                           \
    if (pf) { VMCNT(8); } else { VMCNT(0); }                                   \
    BARW();                                                                    \
  }

// ---------------------------------------------------------------- 256^2 GEMM (stage 3)
__global__ __launch_bounds__(512, 2) void gemm256(const bf16_t* __restrict__ A,
                                                  const bf16_t* __restrict__ Bt,
                                                  void* __restrict__ Cout,
                                                  const float* __restrict__ bias,
                                                  int N, int K, int NB) {
  __shared__ __align__(16) bf16_t sA[2][2][8192];
  __shared__ __align__(16) bf16_t sB[2][2][8192];
  GEMM_MAINLOOP_DECLS();

  const int nwg = gridDim.x;
  const int cpx = nwg >> 3;
  const int bid = blockIdx.x;
  const int swz = (bid & 7) * cpx + (bid >> 3);
  const int m0 = (swz / NB) * 256;
  const int n0 = (swz % NB) * 256;
  const int NT = K >> 6;

  const bf16_t* Abase = A  + (size_t)m0 * K;
  const bf16_t* Bbase = Bt + (size_t)n0 * K;

  GEMM_MAINLOOP_BODY(Abase, Bbase, K, NT);

#pragma unroll
  for (int i = 0; i < 8; ++i) {
#pragma unroll
    for (int jn = 0; jn < 4; ++jn) {
      const int n = n0 + wn * 64 + jn * 16 + lr;
#pragma unroll
      for (int r = 0; r < 4; ++r) {
        const int m = m0 + wm * 128 + i * 16 + g0 * 4 + r;
        ((float*)Cout)[(size_t)m * N + n] = acc[i][jn][r] + bias[n];
      }
    }
  }
}

// ---------------------------------------------------------------- fused v + qp/kp GEMM + block attention
__global__ __launch_bounds__(512, 2) void gemm_fused(const bf16_t* __restrict__ A,
                                                     const bf16_t* __restrict__ Bt,
                                                     const bf16_t* __restrict__ Wv,
                                                     bf16_t* __restrict__ VtG,
                                                     bf16_t* __restrict__ OUT1) {
  __shared__ __align__(16) bf16_t sA[2][2][8192];
  __shared__ __align__(16) bf16_t sB[2][2][8192];
  GEMM_MAINLOOP_DECLS();

  const int nwg = gridDim.x;          // 512
  const int cpx = nwg >> 3;
  const int bid = blockIdx.x;
  const int swz = (bid & 7) * cpx + (bid >> 3);
  const int m0 = (swz >> 3) * 256;
  const int h  = swz & 7;
  const int K  = 1024;
  const int NT = 16;

  const bf16_t* Abase = A  + (size_t)m0 * K;
  const bf16_t* Bbase = Bt + (size_t)(h * 256) * K;
  bf16_t* VtGblk = VtG + (size_t)swz * 32768;   // 64 KB private slot

  // ---------------- phase V: v-GEMM (256 x 128, K=1024) ----------------
  {
    const bf16_t* Wbase = Wv + (size_t)(h * 128) * 1024;
    f32x4 accv[4][4] = {};                 // [mi][di]
    bf16x8 av[4][2], bv[4][2];
    const int wmv = wid >> 1;              // 0..3 -> 64-row strip
    const int wnv = wid & 1;               // 0..1 -> 64-col strip
    const int ah  = wmv >> 1;              // A half
    const int ar0 = (wmv & 1) * 64;

    STAGE_T(sA[0], Abase, 0, 0, K); STAGE_T(sA[0], Abase, 1, 0, K);
    STAGE_T(sB[0], Wbase, 0, 0, K);
    STAGE_T(sA[1], Abase, 0, 1, K); STAGE_T(sA[1], Abase, 1, 1, K);
    STAGE_T(sB[1], Wbase, 0, 1, K);
    VMCNT(6);
    BARW();
#pragma unroll 2
    for (int j = 0; j < NT; ++j) {
      const int cur = j & 1;
      const bool pf = (j + 2) < NT;
#pragma unroll
      for (int mi = 0; mi < 4; ++mi) {
        int r_ = ar0 + mi * 16 + lr;
#pragma unroll
        for (int kh = 0; kh < 2; ++kh) {
          int gl = (g0 + kh * 4) ^ (r_ & 7);
          av[mi][kh] = *(const bf16x8*)(&sA[cur][ah][r_ * 64 + gl * 8]);
        }
      }
#pragma unroll
      for (int di = 0; di < 4; ++di) {
        int r_ = wnv * 64 + di * 16 + lr;
#pragma unroll
        for (int kh = 0; kh < 2; ++kh) {
          int gl = (g0 + kh * 4) ^ (r_ & 7);
          bv[di][kh] = *(const bf16x8*)(&sB[cur][0][r_ * 64 + gl * 8]);
        }
      }
      LGKMN(8); BARW(); LGKM0();
      PRIO(1);
#pragma unroll
      for (int mi = 0; mi < 4; ++mi)
#pragma unroll
        for (int di = 0; di < 2; ++di)
#pragma unroll
          for (int kh = 0; kh < 2; ++kh)
            accv[mi][di] = mfma16x16x32(av[mi][kh], bv[di][kh], accv[mi][di]);
      PRIO(0);
      if (pf) { STAGE_T(sB[cur], Wbase, 0, j + 2, K); }
      BARW();
      PRIO(1);
#pragma unroll
      for (int mi = 0; mi < 4; ++mi)
#pragma unroll
        for (int di = 2; di < 4; ++di)
#pragma unroll
          for (int kh = 0; kh < 2; ++kh)
            accv[mi][di] = mfma16x16x32(av[mi][kh], bv[di][kh], accv[mi][di]);
      PRIO(0);
      if (pf) { STAGE_T(sA[cur], Abase, 0, j + 2, K); STAGE_T(sA[cur], Abase, 1, j + 2, K); }
      if (pf) { VMCNT(6); } else { VMCNT(0); }
      BARW();
    }
    // scatter v (bf16) to private global slot, PRE-SWIZZLED in the [d][m] layout
#pragma unroll
    for (int mi = 0; mi < 4; ++mi)
#pragma unroll
      for (int di = 0; di < 4; ++di) {
        int d  = wnv * 64 + di * 16 + lr;
        int mb = wmv * 64 + mi * 16 + g0 * 4;
        int c  = mb >> 3;
        int g  = (c & 24) | ((c ^ d) & 7);
        bf16x4 pk;
#pragma unroll
        for (int r = 0; r < 4; ++r) pk[r] = (bf16_t)accv[mi][di][r];
        *(bf16x4*)((char*)VtGblk + d * 512 + g * 16 + (mb & 7) * 2) = pk;
      }
    // stores drain under the qp/kp prologue's VMCNT(8)
  }

  // ---------------- phase QK: [qp|kp] main loop ----------------
  GEMM_MAINLOOP_BODY(Abase, Bbase, K, NT);

  // ---------------- fused attention epilogue ----------------
  char* sQb = (char*)(&sA[0][0][0]);   // Qp: 256 rows x 256B (swizzled granules)
  char* sKb = (char*)(&sB[0][0][0]);   // Kp: same; later reused for Vt (128 x 512B)

  // ep1: elu+1, cvt, scatter acc -> LDS
  {
    char* dbase = (wn < 2) ? sQb : sKb;
#pragma unroll
    for (int i = 0; i < 8; ++i)
#pragma unroll
      for (int jn = 0; jn < 4; ++jn)
#pragma unroll
        for (int r = 0; r < 4; ++r) {
          int row = wm * 128 + i * 16 + g0 * 4 + r;
          int col = (wn & 1) * 64 + jn * 16 + lr;     // 0..127 within Q or K
          float v = acc[i][jn][r];
          v = v > 0.f ? v + 1.f : __expf(v);
          int gq = col >> 3;
          int g  = (gq & 8) | ((gq ^ row) & 7);
          *(bf16_t*)(dbase + row * 256 + g * 16 + (col & 7) * 2) = (bf16_t)v;
        }
  }
  LGKM0();
  BARW();

  // ep2a: read ALL S-operand fragments up-front
  const int cb = wm * 4 + wn;          // 0..7, one wave per c-block
  const int rb = cb * 32;
  bf16x8 aS[4][2], bS[4][2];
#pragma unroll
  for (int kh = 0; kh < 4; ++kh) {
#pragma unroll
    for (int t = 0; t < 2; ++t) {
      int row = rb + t * 16 + lr;
      int gq = kh * 4 + g0;
      int g  = (gq & 8) | ((gq ^ row) & 7);
      aS[kh][t] = *(const bf16x8*)(sQb + row * 256 + g * 16);
      bS[kh][t] = *(const bf16x8*)(sKb + row * 256 + g * 16);
    }
  }
  SCHED0(); LGKM0(); BARW();   // all Qp/Kp reads complete; LDS reusable

  // ep2b: stage v slot (L2-hot, pre-swizzled -> linear load) into sKb
  {
#pragma unroll
    for (int l = 0; l < 8; ++l) {
      int gd = l * 512 + tid;
      gld_lds16(VtGblk + (size_t)gd * 8, sKb + gd * 16);
    }
  }
  SCHED0();

  // ep2c: S = qp kp^T (register-only)
  f32x4 sacc[2][2] = {};
#pragma unroll
  for (int kh = 0; kh < 4; ++kh)
#pragma unroll
    for (int mt = 0; mt < 2; ++mt)
#pragma unroll
      for (int nt = 0; nt < 2; ++nt)
        sacc[mt][nt] = mfma16x16x32(aS[kh][mt], bS[kh][nt], sacc[mt][nt]);

  // rowsum over j -> zinv
  float zin[2][4];
#pragma unroll
  for (int mt = 0; mt < 2; ++mt)
#pragma unroll
    for (int r = 0; r < 4; ++r) {
      float s = sacc[mt][0][r] + sacc[mt][1][r];
      s += __shfl_xor(s, 1); s += __shfl_xor(s, 2);
      s += __shfl_xor(s, 4); s += __shfl_xor(s, 8);
      zin[mt][r] = 1.0f / (s + 1e-8f);
    }

  // ep3: P -> Pl (sQb region, 8 x [32 x 80B])
  char* Pl = sQb;
#pragma unroll
  for (int mt = 0; mt < 2; ++mt)
#pragma unroll
    for (int nt = 0; nt < 2; ++nt)
#pragma unroll
      for (int r = 0; r < 4; ++r) {
        int i = mt * 16 + g0 * 4 + r;
        int jj = nt * 16 + lr;
        *(bf16_t*)(Pl + cb * 2560 + i * 80 + jj * 2) =
            (bf16_t)(sacc[mt][nt][r] * zin[mt][r]);
      }
  LGKM0();
  VMCNT(0);
  BARW();

  // ep4: out = P . v  (one MFMA per (mt,dt)), write OUT1
  bf16x8 aP[2];
#pragma unroll
  for (int mt = 0; mt < 2; ++mt)
    aP[mt] = *(const bf16x8*)(Pl + cb * 2560 + (mt * 16 + lr) * 80 + g0 * 16);
#pragma unroll
  for (int dt = 0; dt < 8; ++dt) {
    int row = dt * 16 + lr;
    int gidx = cb * 4 + g0;
    int g = (gidx & 24) | ((gidx ^ row) & 7);
    bf16x8 bV = *(const bf16x8*)(sKb + row * 512 + g * 16);
#pragma unroll
    for (int mt = 0; mt < 2; ++mt) {
      f32x4 z = {};
      f32x4 o = mfma16x16x32(aP[mt], bV, z);
#pragma unroll
      for (int r = 0; r < 4; ++r) {
        int m = m0 + rb + mt * 16 + g0 * 4 + r;
        int d = h * 128 + dt * 16 + lr;
        OUT1[(size_t)m * 1024 + d] = (bf16_t)o[r];
      }
    }
  }
}

// ---------------------------------------------------------------- launch
extern "C" void kernel_launch(void* const* d_in, const int* in_sizes, int n_in,
                              void* d_out, int out_size, void* d_ws, size_t ws_size,
                              hipStream_t stream) {
  const float* x     = (const float*)d_in[0];
  const float* w_qkv = (const float*)d_in[1];
  const float* w_out = (const float*)d_in[2];
  const float* b_out = (const float*)d_in[3];
  const float* proj  = (const float*)d_in[4];
  float* out = (float*)d_out;

  char* ws = (char*)d_ws;
  // layout: xbf [0,32M) | B1t2 [32M,36M) | Wv [36M,38M) | W3t [38M,40M) | VtG [40M,72M) | OUT1 [72M,104M)
  bf16_t* xbf  = (bf16_t*)(ws);
  bf16_t* B1t2 = (bf16_t*)(ws + 33554432);
  bf16_t* Wv   = (bf16_t*)(ws + 37748736);
  bf16_t* W3t  = (bf16_t*)(ws + 39845888);
  bf16_t* VtG  = (bf16_t*)(ws + 41943040);
  bf16_t* OUT1 = (bf16_t*)(ws + 75497472);

  (void)in_sizes; (void)n_in; (void)out_size; (void)ws_size;

  prep<<<3584, 256, 0, stream>>>(w_qkv, proj, w_out, x, B1t2, Wv, W3t, xbf);
  // fused: v-GEMM + [qp|kp] GEMM + block attention -> OUT1[m][1024]
  gemm_fused<<<512, 512, 0, stream>>>(xbf, B1t2, Wv, VtG, OUT1);
  // stage 3: out = OUT1 @ w_out^T + b_out (f32)
  gemm256<<<256, 512, 0, stream>>>(OUT1, W3t, (void*)out, b_out, 1024, 1024, 4);
}

// Round 13
// 197.386 us; speedup vs baseline: 1.0522x; 1.0522x over previous
//
#include <hip/hip_runtime.h>
#include <hip/hip_bf16.h>
#include <stdint.h>
#include <stddef.h>

typedef __bf16 bf16_t;
typedef __bf16 bf16x8 __attribute__((ext_vector_type(8)));
typedef __bf16 bf16x4 __attribute__((ext_vector_type(4)));
typedef float  f32x4  __attribute__((ext_vector_type(4)));

static __device__ __forceinline__ f32x4 mfma16x16x32(bf16x8 a, bf16x8 b, f32x4 c) {
  return __builtin_amdgcn_mfma_f32_16x16x32_bf16(a, b, c, 0, 0, 0);
}

static __device__ __forceinline__ void gld_lds16(const void* g, void* l) {
  __builtin_amdgcn_global_load_lds(
      (const __attribute__((address_space(1))) unsigned int*)g,
      (__attribute__((address_space(3))) unsigned int*)l, 16, 0, 0);
}

#define BARW()   __builtin_amdgcn_s_barrier()
#define SCHED0() __builtin_amdgcn_sched_barrier(0)
#define LGKM0()  asm volatile("s_waitcnt lgkmcnt(0)" ::: "memory")
#define LGKMN(n) asm volatile("s_waitcnt lgkmcnt(" #n ")" ::: "memory")
#define VMCNT(n) asm volatile("s_waitcnt vmcnt(" #n ")" ::: "memory")
#define PRIO(p)  __builtin_amdgcn_s_setprio(p)

// ---------------------------------------------------------------- merged prep:
// [0,1024): fuse_w (16 combos x 16 kt x 4 fq) ; [1024,1280): cvt w_out ;
// [1280,1536): cvt Wv ; [1536,2560): cvt x
__global__ __launch_bounds__(256) void prep(const float* __restrict__ wqkv,
                                            const float* __restrict__ proj,
                                            const float* __restrict__ wout,
                                            const float* __restrict__ x,
                                            bf16_t* __restrict__ B1t2,
                                            bf16_t* __restrict__ Wv,
                                            bf16_t* __restrict__ W3t,
                                            bf16_t* __restrict__ xbf) {
  const int b = blockIdx.x;
  const int tid = threadIdx.x;
  if (b >= 1536) {
    for (int i = (b - 1536) * 256 + tid; i < 4194304; i += 262144) {
      float4 v = *(const float4*)(x + (size_t)i * 4);
      bf16x4 o;
      o[0] = (bf16_t)v.x; o[1] = (bf16_t)v.y; o[2] = (bf16_t)v.z; o[3] = (bf16_t)v.w;
      *(bf16x4*)(xbf + (size_t)i * 4) = o;
    }
    return;
  }
  if (b >= 1024) {
    const float* src = (b < 1280) ? wout : (wqkv + (size_t)2048 * 1024);
    bf16_t* dst = (b < 1280) ? W3t : Wv;
    size_t off = ((size_t)((b - 1024) & 255) * 4096) + tid * 16;
#pragma unroll
    for (int it = 0; it < 4; ++it) {
      float4 v = *(const float4*)(src + off + it * 4);
      bf16x4 o;
      o[0] = (bf16_t)v.x; o[1] = (bf16_t)v.y; o[2] = (bf16_t)v.z; o[3] = (bf16_t)v.w;
      *(bf16x4*)(dst + off + it * 4) = o;
    }
    return;
  }
  // fuse_w: B1t2[h*256 + qk*128 + f][k] = sum_c wqkv[(qk*1024+h*128+c)][k] * proj[h][c][f]
  const int combo = b >> 6;
  const int kt    = (b >> 2) & 15;
  const int fq    = b & 3;
  const int qk    = combo >> 3;
  const int h     = combo & 7;
  const int klocal = tid & 63;
  const int fg     = tid >> 6;
  const int k      = kt * 64 + klocal;

  const float* wbase = wqkv + ((size_t)(qk * 1024 + h * 128)) * 1024 + k;
  const float* pbase = proj + (size_t)h * 16384 + fq * 32 + fg * 8;

  float acc[8];
#pragma unroll
  for (int i = 0; i < 8; ++i) acc[i] = 0.f;

  for (int c = 0; c < 128; ++c) {
    float a = wbase[(size_t)c * 1024];
    const float4* p = (const float4*)(pbase + (size_t)c * 128);
    float4 p0 = p[0], p1 = p[1];
    acc[0] += a * p0.x; acc[1] += a * p0.y; acc[2] += a * p0.z; acc[3] += a * p0.w;
    acc[4] += a * p1.x; acc[5] += a * p1.y; acc[6] += a * p1.z; acc[7] += a * p1.w;
  }
  bf16_t* obase = B1t2 + ((size_t)(h * 256 + qk * 128 + fq * 32 + fg * 8)) * 1024 + k;
#pragma unroll
  for (int i = 0; i < 8; ++i) obase[(size_t)i * 1024] = (bf16_t)acc[i];
}

// ================================================================ shared main-loop macros
#define GEMM_MAINLOOP_DECLS()                                                  \
  const int tid  = threadIdx.x;                                                \
  const int lane = tid & 63;                                                   \
  const int wid  = tid >> 6;                                                   \
  const int wm   = wid >> 2;                                                   \
  const int wn   = wid & 3;                                                    \
  const int lr   = lane & 15;                                                  \
  const int g0   = lane >> 4;                                                  \
  int srow[2], sgl[2];                                                         \
  _Pragma("unroll")                                                            \
  for (int l = 0; l < 2; ++l) {                                                \
    int idx = l * 512 + tid;                                                   \
    srow[l] = idx >> 3;                                                        \
    sgl[l]  = (idx & 7) ^ (srow[l] & 7);                                       \
  }

// arr must be a 2D slice: sA[buf] / sB[buf]
#define STAGE_T(arr, base, half, kt, K_)                                       \
  {                                                                            \
    const bf16_t* s_ = (base) + (size_t)((half) * 128) * (K_) + (kt) * 64;     \
    bf16_t* d_ = &(arr)[half][0];                                              \
    _Pragma("unroll")                                                          \
    for (int l_ = 0; l_ < 2; ++l_)                                             \
      gld_lds16(s_ + (size_t)srow[l_] * (K_) + sgl[l_] * 8,                    \
                d_ + (l_ * 512 + tid) * 8);                                    \
  }

#define RD_A(buf, qm)                                                          \
  _Pragma("unroll")                                                            \
  for (int t_ = 0; t_ < 4; ++t_) {                                             \
    int r_ = (qm) * 64 + t_ * 16 + lr;                                         \
    _Pragma("unroll")                                                          \
    for (int kh_ = 0; kh_ < 2; ++kh_) {                                        \
      int gl_ = (g0 + kh_ * 4) ^ (r_ & 7);                                     \
      a[t_][kh_] = *(const bf16x8*)(&sA[buf][wm][r_ * 64 + gl_ * 8]);          \
    }                                                                          \
  }
#define RD_B(buf, qn, breg)                                                    \
  _Pragma("unroll")                                                            \
  for (int u_ = 0; u_ < 2; ++u_) {                                             \
    int r_ = (wn & 1) * 64 + (qn) * 32 + u_ * 16 + lr;                         \
    _Pragma("unroll")                                                          \
    for (int kh_ = 0; kh_ < 2; ++kh_) {                                        \
      int gl_ = (g0 + kh_ * 4) ^ (r_ & 7);                                     \
      breg[u_][kh_] = *(const bf16x8*)(&sB[buf][wn >> 1][r_ * 64 + gl_ * 8]);  \
    }                                                                          \
  }
#define MMA(qm, qn, breg)                                                      \
  _Pragma("unroll")                                                            \
  for (int mi_ = 0; mi_ < 4; ++mi_)                                            \
    _Pragma("unroll")                                                          \
    for (int nj_ = 0; nj_ < 2; ++nj_)                                          \
      _Pragma("unroll")                                                        \
      for (int kh_ = 0; kh_ < 2; ++kh_)                                        \
        acc[(qm) * 4 + mi_][(qn) * 2 + nj_] =                                  \
            mfma16x16x32(a[mi_][kh_], breg[nj_][kh_],                          \
                         acc[(qm) * 4 + mi_][(qn) * 2 + nj_]);

// R5 best-known 4-phase schedule (counted lgkm pre-barrier waits)
#define GEMM_MAINLOOP_BODY(Abase, Bbase, K_, NT_)                              \
  f32x4 acc[8][4] = {};                                                        \
  bf16x8 a[4][2], b0[2][2], b1[2][2];                                          \
  STAGE_T(sA[0], Abase, 0, 0, K_); STAGE_T(sA[0], Abase, 1, 0, K_);            \
  STAGE_T(sB[0], Bbase, 0, 0, K_); STAGE_T(sB[0], Bbase, 1, 0, K_);            \
  STAGE_T(sA[1], Abase, 0, 1, K_); STAGE_T(sA[1], Abase, 1, 1, K_);            \
  STAGE_T(sB[1], Bbase, 0, 1, K_); STAGE_T(sB[1], Bbase, 1, 1, K_);            \
  VMCNT(8);                                                                    \
  BARW();                                                                      \
  _Pragma("unroll 2")                                                          \
  for (int j = 0; j < (NT_); ++j) {                                            \
    const int cur = j & 1;                                                     \
    const bool pf = (j + 2) < (NT_);                                           \
    RD_A(cur, 0);                                                              \
    RD_B(cur, 0, b0);                                                          \
    SCHED0(); LGKMN(8); BARW(); LGKM0(); SCHED0();                             \
    PRIO(1); MMA(0, 0, b0); PRIO(0);                                           \
    SCHED0(); BARW();                                                          \
    RD_B(cur, 1, b1);                                                          \
    SCHED0(); BARW(); LGKM0(); SCHED0();                                       \
    PRIO(1); MMA(0, 1, b1); PRIO(0);                                           \
    SCHED0(); BARW();                                                          \
    RD_A(cur, 1);                                                              \
    if (pf) { STAGE_T(sB[cur], Bbase, 0, j + 2, K_); STAGE_T(sB[cur], Bbase, 1, j + 2, K_); } \
    SCHED0(); LGKMN(4); BARW(); LGKM0(); SCHED0();                             \
    PRIO(1); MMA(1, 1, b1); PRIO(0);                                           \
    SCHED0(); BARW();                                                          \
    if (pf) { STAGE_T(sA[cur], Abase, 0, j + 2, K_); STAGE_T(sA[cur], Abase, 1, j + 2, K_); } \
    SCHED0(); BARW();                                                          \
    PRIO(1); MMA(1, 0, b0); PRIO(0);                                           \
    if (pf) { VMCNT(8); } else { VMCNT(0); }                                   \
    SCHED0(); BARW();                                                          \
  }

// ---------------------------------------------------------------- 256^2 GEMM (stage 3)
__global__ __launch_bounds__(512, 2) void gemm256(const bf16_t* __restrict__ A,
                                                  const bf16_t* __restrict__ Bt,
                                                  void* __restrict__ Cout,
                                                  const float* __restrict__ bias,
                                                  int N, int K, int NB) {
  __shared__ __align__(16) bf16_t sA[2][2][8192];
  __shared__ __align__(16) bf16_t sB[2][2][8192];
  GEMM_MAINLOOP_DECLS();

  const int nwg = gridDim.x;
  const int cpx = nwg >> 3;
  const int bid = blockIdx.x;
  const int swz = (bid & 7) * cpx + (bid >> 3);
  const int m0 = (swz / NB) * 256;
  const int n0 = (swz % NB) * 256;
  const int NT = K >> 6;

  const bf16_t* Abase = A  + (size_t)m0 * K;
  const bf16_t* Bbase = Bt + (size_t)n0 * K;

  GEMM_MAINLOOP_BODY(Abase, Bbase, K, NT);

#pragma unroll
  for (int i = 0; i < 8; ++i) {
#pragma unroll
    for (int jn = 0; jn < 4; ++jn) {
      const int n = n0 + wn * 64 + jn * 16 + lr;
#pragma unroll
      for (int r = 0; r < 4; ++r) {
        const int m = m0 + wm * 128 + i * 16 + g0 * 4 + r;
        ((float*)Cout)[(size_t)m * N + n] = acc[i][jn][r] + bias[n];
      }
    }
  }
}

// ---------------------------------------------------------------- fused v + qp/kp GEMM + block attention
// Block (mtile, h):
//   phase V: v = x[m0:+256] @ Wv_h^T (256x128), scatter pre-swizzled to private VtG slot
//   phase QK: [qp|kp] (256x256) via main loop
//   epilogue: per 32-row c-block S = qp kp^T, z = rowsum, out = (S/z) v
__global__ __launch_bounds__(512, 2) void gemm_fused(const bf16_t* __restrict__ A,
                                                     const bf16_t* __restrict__ Bt,
                                                     const bf16_t* __restrict__ Wv,
                                                     bf16_t* __restrict__ VtG,
                                                     bf16_t* __restrict__ OUT1) {
  __shared__ __align__(16) bf16_t sA[2][2][8192];
  __shared__ __align__(16) bf16_t sB[2][2][8192];
  GEMM_MAINLOOP_DECLS();

  const int nwg = gridDim.x;          // 512
  const int cpx = nwg >> 3;
  const int bid = blockIdx.x;
  const int swz = (bid & 7) * cpx + (bid >> 3);
  const int m0 = (swz >> 3) * 256;
  const int h  = swz & 7;
  const int K  = 1024;
  const int NT = 16;

  const bf16_t* Abase = A  + (size_t)m0 * K;
  const bf16_t* Bbase = Bt + (size_t)(h * 256) * K;
  bf16_t* VtGblk = VtG + (size_t)swz * 32768;   // 64 KB private slot

  // ---------------- phase V: v-GEMM (256 x 128, K=1024) ----------------
  {
    const bf16_t* Wbase = Wv + (size_t)(h * 128) * 1024;
    f32x4 accv[4][4] = {};                 // [mi][di]
    bf16x8 av[4][2], bv[4][2];
    const int wmv = wid >> 1;              // 0..3 -> 64-row strip
    const int wnv = wid & 1;               // 0..1 -> 64-col strip
    const int ah  = wmv >> 1;              // A half
    const int ar0 = (wmv & 1) * 64;

    STAGE_T(sA[0], Abase, 0, 0, K); STAGE_T(sA[0], Abase, 1, 0, K);
    STAGE_T(sB[0], Wbase, 0, 0, K);
    STAGE_T(sA[1], Abase, 0, 1, K); STAGE_T(sA[1], Abase, 1, 1, K);
    STAGE_T(sB[1], Wbase, 0, 1, K);
    VMCNT(6);
    BARW();
#pragma unroll 2
    for (int j = 0; j < NT; ++j) {
      const int cur = j & 1;
      const bool pf = (j + 2) < NT;
#pragma unroll
      for (int mi = 0; mi < 4; ++mi) {
        int r_ = ar0 + mi * 16 + lr;
#pragma unroll
        for (int kh = 0; kh < 2; ++kh) {
          int gl = (g0 + kh * 4) ^ (r_ & 7);
          av[mi][kh] = *(const bf16x8*)(&sA[cur][ah][r_ * 64 + gl * 8]);
        }
      }
#pragma unroll
      for (int di = 0; di < 4; ++di) {
        int r_ = wnv * 64 + di * 16 + lr;
#pragma unroll
        for (int kh = 0; kh < 2; ++kh) {
          int gl = (g0 + kh * 4) ^ (r_ & 7);
          bv[di][kh] = *(const bf16x8*)(&sB[cur][0][r_ * 64 + gl * 8]);
        }
      }
      SCHED0(); LGKMN(8); BARW(); LGKM0(); SCHED0();
      PRIO(1);
#pragma unroll
      for (int mi = 0; mi < 4; ++mi)
#pragma unroll
        for (int di = 0; di < 2; ++di)
#pragma unroll
          for (int kh = 0; kh < 2; ++kh)
            accv[mi][di] = mfma16x16x32(av[mi][kh], bv[di][kh], accv[mi][di]);
      PRIO(0);
      if (pf) { STAGE_T(sB[cur], Wbase, 0, j + 2, K); }
      SCHED0(); BARW();
      PRIO(1);
#pragma unroll
      for (int mi = 0; mi < 4; ++mi)
#pragma unroll
        for (int di = 2; di < 4; ++di)
#pragma unroll
          for (int kh = 0; kh < 2; ++kh)
            accv[mi][di] = mfma16x16x32(av[mi][kh], bv[di][kh], accv[mi][di]);
      PRIO(0);
      if (pf) { STAGE_T(sA[cur], Abase, 0, j + 2, K); STAGE_T(sA[cur], Abase, 1, j + 2, K); }
      if (pf) { VMCNT(6); } else { VMCNT(0); }
      SCHED0(); BARW();
    }
    // scatter v (bf16) to private global slot, PRE-SWIZZLED in the [d][m] layout
    // ep2b/ep4 expect: granule g of row d holds m-chunk c with g=(c&24)|((c^d)&7)
#pragma unroll
    for (int mi = 0; mi < 4; ++mi)
#pragma unroll
      for (int di = 0; di < 4; ++di) {
        int d  = wnv * 64 + di * 16 + lr;
        int mb = wmv * 64 + mi * 16 + g0 * 4;
        int c  = mb >> 3;
        int g  = (c & 24) | ((c ^ d) & 7);
        bf16x4 pk;
#pragma unroll
        for (int r = 0; r < 4; ++r) pk[r] = (bf16_t)accv[mi][di][r];
        *(bf16x4*)((char*)VtGblk + d * 512 + g * 16 + (mb & 7) * 2) = pk;
      }
    // stores drain under the qp/kp prologue's VMCNT(8) (16 stores are oldest)
  }

  // ---------------- phase QK: [qp|kp] main loop ----------------
  GEMM_MAINLOOP_BODY(Abase, Bbase, K, NT);

  // ---------------- fused attention epilogue ----------------
  char* sQb = (char*)(&sA[0][0][0]);   // Qp: 256 rows x 256B (swizzled granules)
  char* sKb = (char*)(&sB[0][0][0]);   // Kp: same; later reused for Vt (128 x 512B)

  // ep1: elu+1, cvt, scatter acc -> LDS
  {
    char* dbase = (wn < 2) ? sQb : sKb;
#pragma unroll
    for (int i = 0; i < 8; ++i)
#pragma unroll
      for (int jn = 0; jn < 4; ++jn)
#pragma unroll
        for (int r = 0; r < 4; ++r) {
          int row = wm * 128 + i * 16 + g0 * 4 + r;
          int col = (wn & 1) * 64 + jn * 16 + lr;     // 0..127 within Q or K
          float v = acc[i][jn][r];
          v = v > 0.f ? v + 1.f : __expf(v);
          int gq = col >> 3;
          int g  = (gq & 8) | ((gq ^ row) & 7);
          *(bf16_t*)(dbase + row * 256 + g * 16 + (col & 7) * 2) = (bf16_t)v;
        }
  }
  LGKM0();
  BARW();

  // ep2a: read ALL S-operand fragments up-front
  const int cb = wm * 4 + wn;          // 0..7, one wave per c-block
  const int rb = cb * 32;
  bf16x8 aS[4][2], bS[4][2];
#pragma unroll
  for (int kh = 0; kh < 4; ++kh) {
#pragma unroll
    for (int t = 0; t < 2; ++t) {
      int row = rb + t * 16 + lr;
      int gq = kh * 4 + g0;
      int g  = (gq & 8) | ((gq ^ row) & 7);
      aS[kh][t] = *(const bf16x8*)(sQb + row * 256 + g * 16);
      bS[kh][t] = *(const bf16x8*)(sKb + row * 256 + g * 16);
    }
  }
  SCHED0(); LGKM0(); BARW();   // all Qp/Kp reads complete; LDS reusable

  // ep2b: stage v slot (L2-hot, pre-swizzled -> linear load) into sKb
  {
#pragma unroll
    for (int l = 0; l < 8; ++l) {
      int gd = l * 512 + tid;
      gld_lds16(VtGblk + (size_t)gd * 8, sKb + gd * 16);
    }
  }
  SCHED0();

  // ep2c: S = qp kp^T (register-only)
  f32x4 sacc[2][2] = {};
#pragma unroll
  for (int kh = 0; kh < 4; ++kh)
#pragma unroll
    for (int mt = 0; mt < 2; ++mt)
#pragma unroll
      for (int nt = 0; nt < 2; ++nt)
        sacc[mt][nt] = mfma16x16x32(aS[kh][mt], bS[kh][nt], sacc[mt][nt]);

  // rowsum over j -> zinv
  float zin[2][4];
#pragma unroll
  for (int mt = 0; mt < 2; ++mt)
#pragma unroll
    for (int r = 0; r < 4; ++r) {
      float s = sacc[mt][0][r] + sacc[mt][1][r];
      s += __shfl_xor(s, 1); s += __shfl_xor(s, 2);
      s += __shfl_xor(s, 4); s += __shfl_xor(s, 8);
      zin[mt][r] = 1.0f / (s + 1e-8f);
    }

  // ep3: P -> Pl (sQb region, 8 x [32 x 80B])
  char* Pl = sQb;
#pragma unroll
  for (int mt = 0; mt < 2; ++mt)
#pragma unroll
    for (int nt = 0; nt < 2; ++nt)
#pragma unroll
      for (int r = 0; r < 4; ++r) {
        int i = mt * 16 + g0 * 4 + r;
        int jj = nt * 16 + lr;
        *(bf16_t*)(Pl + cb * 2560 + i * 80 + jj * 2) =
            (bf16_t)(sacc[mt][nt][r] * zin[mt][r]);
      }
  LGKM0();
  VMCNT(0);
  BARW();

  // ep4: out = P . v  (one MFMA per (mt,dt)), write OUT1
  bf16x8 aP[2];
#pragma unroll
  for (int mt = 0; mt < 2; ++mt)
    aP[mt] = *(const bf16x8*)(Pl + cb * 2560 + (mt * 16 + lr) * 80 + g0 * 16);
#pragma unroll
  for (int dt = 0; dt < 8; ++dt) {
    int row = dt * 16 + lr;
    int gidx = cb * 4 + g0;
    int g = (gidx & 24) | ((gidx ^ row) & 7);
    bf16x8 bV = *(const bf16x8*)(sKb + row * 512 + g * 16);
#pragma unroll
    for (int mt = 0; mt < 2; ++mt) {
      f32x4 z = {};
      f32x4 o = mfma16x16x32(aP[mt], bV, z);
#pragma unroll
      for (int r = 0; r < 4; ++r) {
        int m = m0 + rb + mt * 16 + g0 * 4 + r;
        int d = h * 128 + dt * 16 + lr;
        OUT1[(size_t)m * 1024 + d] = (bf16_t)o[r];
      }
    }
  }
}

// ---------------------------------------------------------------- launch
extern "C" void kernel_launch(void* const* d_in, const int* in_sizes, int n_in,
                              void* d_out, int out_size, void* d_ws, size_t ws_size,
                              hipStream_t stream) {
  const float* x     = (const float*)d_in[0];
  const float* w_qkv = (const float*)d_in[1];
  const float* w_out = (const float*)d_in[2];
  const float* b_out = (const float*)d_in[3];
  const float* proj  = (const float*)d_in[4];
  float* out = (float*)d_out;

  char* ws = (char*)d_ws;
  // layout: xbf [0,32M) | B1t2 [32M,36M) | Wv [36M,38M) | W3t [38M,40M) | VtG [40M,72M) | OUT1 [72M,104M)
  bf16_t* xbf  = (bf16_t*)(ws);
  bf16_t* B1t2 = (bf16_t*)(ws + 33554432);
  bf16_t* Wv   = (bf16_t*)(ws + 37748736);
  bf16_t* W3t  = (bf16_t*)(ws + 39845888);
  bf16_t* VtG  = (bf16_t*)(ws + 41943040);
  bf16_t* OUT1 = (bf16_t*)(ws + 75497472);

  (void)in_sizes; (void)n_in; (void)out_size; (void)ws_size;

  prep<<<2560, 256, 0, stream>>>(w_qkv, proj, w_out, x, B1t2, Wv, W3t, xbf);
  // fused: v-GEMM + [qp|kp] GEMM + block attention -> OUT1[m][1024]
  gemm_fused<<<512, 512, 0, stream>>>(xbf, B1t2, Wv, VtG, OUT1);
  // stage 3: out = OUT1 @ w_out^T + b_out (f32)
  gemm256<<<256, 512, 0, stream>>>(OUT1, W3t, (void*)out, b_out, 1024, 1024, 4);
}